// Round 5
// baseline (774.748 us; speedup 1.0000x reference)
//
#include <hip/hip_runtime.h>
#include <math.h>

#define NB    64
#define DIM   256
#define TWOD  512
#define CNTE  1000

typedef __attribute__((ext_vector_type(8))) short short8;
typedef __attribute__((ext_vector_type(4))) float f32x4;

union U16x8 { uint4 u; short8 s; };

__device__ __forceinline__ unsigned short f2bf(float x) {
    unsigned int u = __float_as_uint(x);
    u += 0x7fffu + ((u >> 16) & 1u);          // round-to-nearest-even
    return (unsigned short)(u >> 16);
}
__device__ __forceinline__ float bf2f(unsigned short h) {
    return __uint_as_float(((unsigned int)h) << 16);
}
__device__ __forceinline__ float tanh_fast(float x) {
    float e = __expf(2.0f * x);
    return 1.0f - 2.0f / (e + 1.0f);
}

// ---- precompute: FULL attn_W (512x512) -> bf16 in MFMA B-fragment order ----
// frag f = ((ot*16 + kt)*64 + lane)*8 + j  ->  o = ot*16 + (lane&15),
// k = kt*32 + (lane>>4)*8 + j
__global__ __launch_bounds__(256) void pack_w_kernel(
    const float* __restrict__ attn_W, unsigned short* __restrict__ wbf)
{
    int f = blockIdx.x * 256 + threadIdx.x;           // 0..262143
    int j    = f & 7;
    int lane = (f >> 3) & 63;
    int kt   = (f >> 9) & 15;
    int ot   = f >> 13;                               // 0..31
    int o = ot * 16 + (lane & 15);
    int k = kt * 32 + (lane >> 4) * 8 + j;
    wbf[f] = f2bf(attn_W[(size_t)o * TWOD + k]);
}

// ---- main fused kernel: one block per batch element ----
// e2 is stored in MFMA A-fragment order so streaming reads are
// lane-contiguous (conflict-free ds_read_b128):
//   elem(m,k): off = (((m>>4)*8 + (k>>5))*64 + ((k>>3)&3)*16 + (m&15))*8 + (k&7)
__global__ __launch_bounds__(256, 3) void encoder_attn_kernel(
    const int*   __restrict__ nei_rid,   // [B,64]
    const float* __restrict__ nei_e,     // [B,64,256]
    const float* __restrict__ nei_rw,    // [B,64]
    const int*   __restrict__ q_rid,     // [B]
    const float* __restrict__ w_r,       // [1001,256]
    const float* __restrict__ zq_w,      // [1000,256]
    const float* __restrict__ attn_b,    // [512]
    const float* __restrict__ u_a_w,     // [512]
    const float* __restrict__ u_a_b,     // [1]
    const unsigned short* __restrict__ wbf,   // [32][16][64][8] bf16 B-frags (K=512)
    float*       __restrict__ out)       // [B,256]
{
    __shared__ __align__(16) unsigned short e2[NB * DIM];  // frag-ordered, 32768 B
    __shared__ __align__(16) unsigned short zq2[DIM];      // 512 B
    __shared__ float2 bua[TWOD];                           // (attn_b, u_a) 4 KB
    __shared__ float  red_a[256];
    __shared__ float  pen[NB];
    __shared__ float  attn_lds[NB];

    const int b = blockIdx.x;
    const int t = threadIdx.x;

    const int qr = q_rid[b];
    bua[t]       = make_float2(attn_b[t],       u_a_w[t]);
    bua[t + 256] = make_float2(attn_b[t + 256], u_a_w[t + 256]);
    zq2[t] = f2bf(zq_w[(size_t)qr * DIM + t]);

    // ---- phase 1: TransH projection (4 threads per neighbor) ----
    const int n = t >> 2, q = t & 3;
    const int rid = nei_rid[b * NB + n];
    const float4* e4 = (const float4*)(nei_e + ((size_t)(b * NB + n)) * DIM) + q * 16;
    const float4* w4 = (const float4*)(w_r + (size_t)rid * DIM) + q * 16;
    {
        float4 ev[16], wv[16];
        float sew = 0.f, sww = 0.f;
        #pragma unroll
        for (int j = 0; j < 16; ++j) {
            ev[j] = e4[j]; wv[j] = w4[j];
            sew += ev[j].x * wv[j].x + ev[j].y * wv[j].y + ev[j].z * wv[j].z + ev[j].w * wv[j].w;
            sww += wv[j].x * wv[j].x + wv[j].y * wv[j].y + wv[j].z * wv[j].z + wv[j].w * wv[j].w;
        }
        sew += __shfl_xor(sew, 1); sew += __shfl_xor(sew, 2);
        sww += __shfl_xor(sww, 1); sww += __shfl_xor(sww, 2);
        float nc   = fmaxf(sqrtf(sww), 1e-12f);
        float coef = sew / (nc * nc);
        float maskf = (rid < CNTE) ? 1.f : 0.f;
        if (q == 0) pen[n] = (rid == CNTE) ? 1e19f : 0.f;
        const int mt1 = n >> 4, l15n = n & 15;
        #pragma unroll
        for (int jj = 0; jj < 8; ++jj) {
            float4 e0 = ev[jj * 2],     w0 = wv[jj * 2];
            float4 e1 = ev[jj * 2 + 1], w1 = wv[jj * 2 + 1];
            uint4 pk;
            pk.x = (unsigned int)f2bf((e0.x - coef * w0.x) * maskf)
                 | ((unsigned int)f2bf((e0.y - coef * w0.y) * maskf) << 16);
            pk.y = (unsigned int)f2bf((e0.z - coef * w0.z) * maskf)
                 | ((unsigned int)f2bf((e0.w - coef * w0.w) * maskf) << 16);
            pk.z = (unsigned int)f2bf((e1.x - coef * w1.x) * maskf)
                 | ((unsigned int)f2bf((e1.y - coef * w1.y) * maskf) << 16);
            pk.w = (unsigned int)f2bf((e1.z - coef * w1.z) * maskf)
                 | ((unsigned int)f2bf((e1.w - coef * w1.w) * maskf) << 16);
            // k-chunk = q*64 + jj*8 -> kt = 2q + (jj>>2), lq = jj&3
            int kt = 2 * q + (jj >> 2);
            int lq = jj & 3;
            int off = (((mt1 * 8 + kt) * 64) + lq * 16 + l15n) * 8;
            *(uint4*)(e2 + off) = pk;
        }
    }
    __syncthreads();   // e2 + zq2 + bua ready

    // ---- phase 3: MFMA GEMM, K=512: A = [zq (broadcast rows) | e_tr] ----
    const int wv_id = t >> 6;        // wave -> o range [wv_id*128, +128)
    const int lane  = t & 63;
    const int l15 = lane & 15, lq = lane >> 4;

    f32x4 lpv[4];
    #pragma unroll
    for (int mt = 0; mt < 4; ++mt) lpv[mt] = (f32x4){0.f, 0.f, 0.f, 0.f};

    #pragma unroll 1
    for (int ot = 0; ot < 8; ++ot) {
        const int otg = wv_id * 8 + ot;
        const uint4* wp = (const uint4*)wbf + (size_t)(otg * 16) * 64 + lane;
        short8 bz[8], be[8];
        #pragma unroll
        for (int kt = 0; kt < 8; ++kt) { U16x8 u; u.u = wp[kt * 64]; bz[kt] = u.s; }
        #pragma unroll
        for (int kt = 0; kt < 8; ++kt) { U16x8 u; u.u = wp[(kt + 8) * 64]; be[kt] = u.s; }

        // z-half: rows identical -> one acc chain shared by all row-tiles
        f32x4 accz = (f32x4){0.f, 0.f, 0.f, 0.f};
        #pragma unroll
        for (int kt = 0; kt < 8; ++kt) {
            U16x8 u; u.u = *(const uint4*)(zq2 + kt * 32 + lq * 8);  // 4-addr broadcast
            accz = __builtin_amdgcn_mfma_f32_16x16x32_bf16(u.s, bz[kt], accz, 0, 0, 0);
        }
        f32x4 acc[4];
        #pragma unroll
        for (int mt = 0; mt < 4; ++mt) acc[mt] = accz;
        // e-half: stream A-frags from LDS (lane-contiguous b128, conflict-free)
        #pragma unroll
        for (int kt = 0; kt < 8; ++kt) {
            short8 a0, a1, a2, a3;
            { U16x8 u; u.u = *(const uint4*)(e2 + ((0 * 8 + kt) * 64 + lane) * 8); a0 = u.s; }
            { U16x8 u; u.u = *(const uint4*)(e2 + ((1 * 8 + kt) * 64 + lane) * 8); a1 = u.s; }
            { U16x8 u; u.u = *(const uint4*)(e2 + ((2 * 8 + kt) * 64 + lane) * 8); a2 = u.s; }
            { U16x8 u; u.u = *(const uint4*)(e2 + ((3 * 8 + kt) * 64 + lane) * 8); a3 = u.s; }
            acc[0] = __builtin_amdgcn_mfma_f32_16x16x32_bf16(a0, be[kt], acc[0], 0, 0, 0);
            acc[1] = __builtin_amdgcn_mfma_f32_16x16x32_bf16(a1, be[kt], acc[1], 0, 0, 0);
            acc[2] = __builtin_amdgcn_mfma_f32_16x16x32_bf16(a2, be[kt], acc[2], 0, 0, 0);
            acc[3] = __builtin_amdgcn_mfma_f32_16x16x32_bf16(a3, be[kt], acc[3], 0, 0, 0);
        }
        float2 zu = bua[otg * 16 + l15];   // (bias, u_a) for this lane's o
        #pragma unroll
        for (int mt = 0; mt < 4; ++mt)
            #pragma unroll
            for (int r = 0; r < 4; ++r) {
                float h = tanh_fast(acc[mt][r] + zu.x);
                lpv[mt][r] += zu.y * h;
            }
    }

    // ---- logit reduction over l15 (16 col-slots) via shuffles ----
    #pragma unroll
    for (int mt = 0; mt < 4; ++mt)
        #pragma unroll
        for (int r = 0; r < 4; ++r) {
            float v = lpv[mt][r];
            v += __shfl_xor(v, 1); v += __shfl_xor(v, 2);
            v += __shfl_xor(v, 4); v += __shfl_xor(v, 8);
            if (l15 == 0) red_a[wv_id * 64 + mt * 16 + lq * 4 + r] = v;
        }
    __syncthreads();

    // ---- phase 4: softmax over 64 neighbors (wave 0) ----
    if (t < NB) {
        float lgt = red_a[t] + red_a[64 + t] + red_a[128 + t] + red_a[192 + t]
                  + u_a_b[0] - pen[t];
        float m = lgt;
        #pragma unroll
        for (int off = 32; off > 0; off >>= 1) m = fmaxf(m, __shfl_xor(m, off));
        float ex = __expf(lgt - m);
        float s = ex;
        #pragma unroll
        for (int off = 32; off > 0; off >>= 1) s += __shfl_xor(s, off);
        attn_lds[t] = ex / s + nei_rw[b * NB + t];
    }
    __syncthreads();

    // ---- phase 5: out[k] = sum_m attn[m] * e_tr[m][k], frag layout ----
    // wave wv covers kt in {2wv, 2wv+1}; lane reads (m-slot l15, k-chunk lq).
    #pragma unroll
    for (int ktl = 0; ktl < 2; ++ktl) {
        const int kt = wv_id * 2 + ktl;
        float vacc[8];
        #pragma unroll
        for (int j = 0; j < 8; ++j) vacc[j] = 0.f;
        #pragma unroll
        for (int mt = 0; mt < 4; ++mt) {
            U16x8 u; u.u = *(const uint4*)(e2 + ((mt * 8 + kt) * 64 + lane) * 8);
            float an = attn_lds[mt * 16 + l15];
            #pragma unroll
            for (int j = 0; j < 8; ++j)
                vacc[j] += an * bf2f((unsigned short)u.s[j]);
        }
        #pragma unroll
        for (int j = 0; j < 8; ++j) {
            vacc[j] += __shfl_xor(vacc[j], 1);
            vacc[j] += __shfl_xor(vacc[j], 2);
            vacc[j] += __shfl_xor(vacc[j], 4);
            vacc[j] += __shfl_xor(vacc[j], 8);
        }
        if (l15 == 0) {
            float* op = out + (size_t)b * DIM + kt * 32 + lq * 8;
            ((float4*)op)[0] = make_float4(vacc[0], vacc[1], vacc[2], vacc[3]);
            ((float4*)op)[1] = make_float4(vacc[4], vacc[5], vacc[6], vacc[7]);
        }
    }
}

extern "C" void kernel_launch(void* const* d_in, const int* in_sizes, int n_in,
                              void* d_out, int out_size, void* d_ws, size_t ws_size,
                              hipStream_t stream) {
    const int*   nei_rid = (const int*)  d_in[0];
    const float* nei_e   = (const float*)d_in[1];
    const float* nei_rw  = (const float*)d_in[2];
    const int*   q_rid   = (const int*)  d_in[3];
    const float* w_r     = (const float*)d_in[4];
    const float* zq_w    = (const float*)d_in[5];
    const float* attn_W  = (const float*)d_in[6];
    const float* attn_b  = (const float*)d_in[7];
    const float* u_a_w   = (const float*)d_in[8];
    const float* u_a_b   = (const float*)d_in[9];
    float* out = (float*)d_out;

    const int B = in_sizes[3];               // 4096

    unsigned short* wbf = (unsigned short*)d_ws;   // 512 KB (K=512 pack)

    hipLaunchKernelGGL(pack_w_kernel, dim3(1024), dim3(256), 0, stream, attn_W, wbf);
    hipLaunchKernelGGL(encoder_attn_kernel, dim3(B), dim3(256), 0, stream,
                       nei_rid, nei_e, nei_rw, q_rid, w_r, zq_w,
                       attn_b, u_a_w, u_a_b, wbf, out);
}